// Round 2
// baseline (461.985 us; speedup 1.0000x reference)
//
#include <hip/hip_runtime.h>

#define N_F_IN   16
#define N_F_OUT  16
#define N_EFEAT  8
#define N_HIDDEN 32

// -------- kernel A: out[n,:] = x[n]@root_kernel + bias  (deterministic init of output)
__global__ __launch_bounds__(256) void root_init_kernel(
    const float* __restrict__ x,       // [N,16]
    const float* __restrict__ rootk,   // [16,16]
    const float* __restrict__ bias,    // [16]
    float* __restrict__ out,           // [N,16]
    int n_nodes)
{
    __shared__ float sR[N_F_IN * N_F_OUT];
    __shared__ float sB[N_F_OUT];
    if (threadIdx.x < 256) sR[threadIdx.x] = rootk[threadIdx.x];
    if (threadIdx.x < 16)  sB[threadIdx.x] = bias[threadIdx.x];
    __syncthreads();

    int nid = blockIdx.x * 256 + threadIdx.x;
    if (nid >= n_nodes) return;

    const float* xp = x + (size_t)nid * 16;
    float xf[16];
#pragma unroll
    for (int f = 0; f < 16; f += 4) {
        float4 v = *reinterpret_cast<const float4*>(xp + f);
        xf[f] = v.x; xf[f + 1] = v.y; xf[f + 2] = v.z; xf[f + 3] = v.w;
    }

    float o[16];
#pragma unroll
    for (int c = 0; c < 16; ++c) o[c] = sB[c];
#pragma unroll
    for (int f = 0; f < 16; ++f) {
        float p = xf[f];
#pragma unroll
        for (int c = 0; c < 16; ++c)
            o[c] = fmaf(p, sR[f * 16 + c], o[c]);
    }

    float* dst = out + (size_t)nid * 16;
#pragma unroll
    for (int c = 0; c < 16; c += 4) {
        *reinterpret_cast<float4*>(dst + c) = make_float4(o[c], o[c+1], o[c+2], o[c+3]);
    }
}

// -------- kernel B: per-edge fused filter-gen + message + scatter-add
__global__ __launch_bounds__(256) void edge_kernel(
    const float* __restrict__ x,      // [N,16]
    const float* __restrict__ efeat,  // [E,8]
    const int*   __restrict__ idx_i,  // targets
    const int*   __restrict__ idx_j,  // sources
    const float* __restrict__ W1,     // [8,32]
    const float* __restrict__ b1,     // [32]
    const float* __restrict__ W2,     // [32,256]
    const float* __restrict__ b2,     // [256]
    float* __restrict__ out,          // [N,16] f32, pre-initialized with root term
    int n_edges)
{
    __shared__ __align__(16) float sW2[N_HIDDEN * 256];   // 32KB
    __shared__ __align__(16) float sW1[N_EFEAT * N_HIDDEN];
    __shared__ __align__(16) float sb1[N_HIDDEN];
    __shared__ __align__(16) float sb2[256];

    for (int i = threadIdx.x; i < N_HIDDEN * 256; i += 256) sW2[i] = W2[i];
    if (threadIdx.x < 256) {
        sW1[threadIdx.x] = W1[threadIdx.x];  // 8*32 = 256
        sb2[threadIdx.x] = b2[threadIdx.x];
    }
    if (threadIdx.x < 32) sb1[threadIdx.x] = b1[threadIdx.x];
    __syncthreads();

    int eid = blockIdx.x * 256 + threadIdx.x;
    if (eid >= n_edges) return;

    // edge features (8 f32 = 32B, aligned)
    const float* ep = efeat + (size_t)eid * 8;
    float ef[8];
#pragma unroll
    for (int k = 0; k < 8; k += 4) {
        float4 v = *reinterpret_cast<const float4*>(ep + k);
        ef[k] = v.x; ef[k + 1] = v.y; ef[k + 2] = v.z; ef[k + 3] = v.w;
    }

    int j  = idx_j[eid];
    int it = idx_i[eid];

    // gathered source node features
    const float* xp = x + (size_t)j * 16;
    float xf[16];
#pragma unroll
    for (int f = 0; f < 16; f += 4) {
        float4 v = *reinterpret_cast<const float4*>(xp + f);
        xf[f] = v.x; xf[f + 1] = v.y; xf[f + 2] = v.z; xf[f + 3] = v.w;
    }

    float msg[16];
#pragma unroll
    for (int c = 0; c < 16; ++c) msg[c] = 0.f;

    // main contraction: msg[c] += relu(e@W1+b1)[hd] * x[f] * W2[hd, f*16+c]
#pragma unroll 1
    for (int hd = 0; hd < N_HIDDEN; ++hd) {
        float hv = sb1[hd];
#pragma unroll
        for (int k = 0; k < 8; ++k)
            hv = fmaf(ef[k], sW1[k * 32 + hd], hv);
        hv = fmaxf(hv, 0.f);

        const float* wrow = sW2 + hd * 256;
#pragma unroll
        for (int f = 0; f < 16; ++f) {
            float p = hv * xf[f];
#pragma unroll
            for (int c = 0; c < 16; c += 4) {
                float4 wv = *reinterpret_cast<const float4*>(wrow + f * 16 + c);
                msg[c + 0] = fmaf(p, wv.x, msg[c + 0]);
                msg[c + 1] = fmaf(p, wv.y, msg[c + 1]);
                msg[c + 2] = fmaf(p, wv.z, msg[c + 2]);
                msg[c + 3] = fmaf(p, wv.w, msg[c + 3]);
            }
        }
    }

    // b2 contribution: msg[c] += sum_f x[f] * b2[f*16+c]
#pragma unroll
    for (int f = 0; f < 16; ++f) {
        float p = xf[f];
#pragma unroll
        for (int c = 0; c < 16; c += 4) {
            float4 bv = *reinterpret_cast<const float4*>(sb2 + f * 16 + c);
            msg[c + 0] = fmaf(p, bv.x, msg[c + 0]);
            msg[c + 1] = fmaf(p, bv.y, msg[c + 1]);
            msg[c + 2] = fmaf(p, bv.z, msg[c + 2]);
            msg[c + 3] = fmaf(p, bv.w, msg[c + 3]);
        }
    }

    // scatter-add to target node
    float* dst = out + (size_t)it * 16;
#pragma unroll
    for (int c = 0; c < 16; ++c)
        atomicAdd(dst + c, msg[c]);
}

extern "C" void kernel_launch(void* const* d_in, const int* in_sizes, int n_in,
                              void* d_out, int out_size, void* d_ws, size_t ws_size,
                              hipStream_t stream) {
    const float* x     = (const float*)d_in[0];
    const float* e     = (const float*)d_in[1];
    const int*   idx_i = (const int*)d_in[2];
    const int*   idx_j = (const int*)d_in[3];
    const float* W1    = (const float*)d_in[4];
    const float* b1    = (const float*)d_in[5];
    const float* W2    = (const float*)d_in[6];
    const float* b2    = (const float*)d_in[7];
    const float* rootk = (const float*)d_in[8];
    const float* bias  = (const float*)d_in[9];

    int n_nodes = in_sizes[0] / 16;
    int n_edges = in_sizes[2];

    float* out = (float*)d_out;

    int blocksA = (n_nodes + 255) / 256;
    root_init_kernel<<<blocksA, 256, 0, stream>>>(x, rootk, bias, out, n_nodes);

    int blocksB = (n_edges + 255) / 256;
    edge_kernel<<<blocksB, 256, 0, stream>>>(x, e, idx_i, idx_j, W1, b1, W2, b2, out, n_edges);
}

// Round 3
// 77.465 us; speedup vs baseline: 5.9638x; 5.9638x over previous
//
#include <hip/hip_runtime.h>

#define N_F_IN   16
#define N_F_OUT  16
#define N_EFEAT  8
#define N_HIDDEN 32

typedef __attribute__((ext_vector_type(8))) short bf16x8_t;   // 8 bf16 (4 VGPRs)
typedef __attribute__((ext_vector_type(4))) float f32x4_t;    // MFMA accumulator

__device__ __forceinline__ unsigned short f2bf(float f) {
    union { float f; unsigned int i; } v;
    v.f = f;
    unsigned int u = v.i;
    unsigned int r = (u + 0x7FFFu + ((u >> 16) & 1u)) >> 16;   // RNE
    return (unsigned short)r;
}

// -------- kernel A: out[n,:] = x[n]@root_kernel + bias  (deterministic init of output)
__global__ __launch_bounds__(256) void root_init_kernel(
    const float* __restrict__ x,       // [N,16]
    const float* __restrict__ rootk,   // [16,16]
    const float* __restrict__ bias,    // [16]
    float* __restrict__ out,           // [N,16]
    int n_nodes)
{
    __shared__ float sR[N_F_IN * N_F_OUT];
    __shared__ float sB[N_F_OUT];
    if (threadIdx.x < 256) sR[threadIdx.x] = rootk[threadIdx.x];
    if (threadIdx.x < 16)  sB[threadIdx.x] = bias[threadIdx.x];
    __syncthreads();

    int nid = blockIdx.x * 256 + threadIdx.x;
    if (nid >= n_nodes) return;

    const float* xp = x + (size_t)nid * 16;
    float xf[16];
#pragma unroll
    for (int f = 0; f < 16; f += 4) {
        float4 v = *reinterpret_cast<const float4*>(xp + f);
        xf[f] = v.x; xf[f + 1] = v.y; xf[f + 2] = v.z; xf[f + 3] = v.w;
    }

    float o[16];
#pragma unroll
    for (int c = 0; c < 16; ++c) o[c] = sB[c];
#pragma unroll
    for (int f = 0; f < 16; ++f) {
        float p = xf[f];
#pragma unroll
        for (int c = 0; c < 16; ++c)
            o[c] = fmaf(p, sR[f * 16 + c], o[c]);
    }

    float* dst = out + (size_t)nid * 16;
#pragma unroll
    for (int c = 0; c < 16; c += 4)
        *reinterpret_cast<float4*>(dst + c) = make_float4(o[c], o[c+1], o[c+2], o[c+3]);
}

// -------- kernel B: MFMA edge kernel. One wave = 16 edges per group, grid-stride over groups.
// msg = z @ W2r, z[e, hd*16+f] = h[e,hd]*x[e,f], W2r[hd*16+f, c] = W2[hd, f*16+c].
// K = 512 (+16 for the b2 fold) => 16 MFMA K-steps + 1.
__global__ __launch_bounds__(256) void edge_mfma_kernel(
    const float* __restrict__ x,      // [N,16]
    const float* __restrict__ efeat,  // [E,8]
    const int*   __restrict__ idx_i,  // targets
    const int*   __restrict__ idx_j,  // sources
    const float* __restrict__ W1,     // [8,32]
    const float* __restrict__ b1,     // [32]
    const float* __restrict__ W2,     // [32,256]
    const float* __restrict__ b2,     // [256]
    float* __restrict__ out,          // [N,16] f32, pre-initialized with root term
    int n_edges, int n_groups)
{
    __shared__ float sW1[N_EFEAT * N_HIDDEN];   // [8][32]
    __shared__ float sb1[N_HIDDEN];
    if (threadIdx.x < 256) sW1[threadIdx.x] = W1[threadIdx.x];
    if (threadIdx.x < 32)  sb1[threadIdx.x] = b1[threadIdx.x];
    __syncthreads();

    const int lane = threadIdx.x & 63;
    const int q    = lane >> 4;      // 0..3  (K-group of the fragment)
    const int c    = lane & 15;      // B col / A row (edge slot), per 16x16 layout
    const int hpar = q >> 1;         // 0: even hidden units, 1: odd
    const int f0   = (q & 1) * 8;    // which half of the 16 input features

    // ---- B-fragment preload (once per wave, reused across all groups) ----
    // B layout: lane supplies B[k = s*32 + q*8 + j][col = c], k = hd*16 + f
    //   -> hd = 2s + hpar, f = f0 + j.
    bf16x8_t bfrag[17];
#pragma unroll
    for (int s = 0; s < 16; ++s) {
        const float* wp = W2 + (2 * s + hpar) * 256 + f0 * 16 + c;
        bf16x8_t bv;
#pragma unroll
        for (int jj = 0; jj < 8; ++jj)
            bv[jj] = (short)f2bf(wp[jj * 16]);
        bfrag[s] = bv;
    }
    {
        // b2 fold: K-step 16, rows k'=0..15 hold b2[f*16+c], rows 16..31 are zero.
        bf16x8_t bv;
#pragma unroll
        for (int jj = 0; jj < 8; ++jj)
            bv[jj] = (hpar == 0) ? (short)f2bf(b2[(f0 + jj) * 16 + c]) : (short)0;
        bfrag[16] = bv;
    }

    const int gwave  = blockIdx.x * 4 + (threadIdx.x >> 6);
    const int nwaves = gridDim.x * 4;

    for (int g = gwave; g < n_groups; g += nwaves) {
        const int base = g * 16;

        // ---- per-edge data: this lane serves edge row e = c (A row = lane&15) ----
        const int eid_a = base + c;
        const bool va   = (eid_a < n_edges);
        const int  j    = va ? idx_j[eid_a] : 0;
        const int  eldc = va ? eid_a : 0;

        // x[j, f0..f0+7] (f32 + bf16 copy for the b2 step)
        float xf[8];
        {
            const float* xp = x + (size_t)j * 16 + f0;
            float4 v0 = *reinterpret_cast<const float4*>(xp);
            float4 v1 = *reinterpret_cast<const float4*>(xp + 4);
            xf[0] = v0.x; xf[1] = v0.y; xf[2] = v0.z; xf[3] = v0.w;
            xf[4] = v1.x; xf[5] = v1.y; xf[6] = v1.z; xf[7] = v1.w;
            if (!va) {
#pragma unroll
                for (int t = 0; t < 8; ++t) xf[t] = 0.f;   // invalid edge -> z = 0
            }
        }
        bf16x8_t xbf;
#pragma unroll
        for (int t = 0; t < 8; ++t) xbf[t] = (short)f2bf(xf[t]);

        // edge features
        float ef[8];
        {
            const float* ep = efeat + (size_t)eldc * 8;
            float4 v0 = *reinterpret_cast<const float4*>(ep);
            float4 v1 = *reinterpret_cast<const float4*>(ep + 4);
            ef[0] = v0.x; ef[1] = v0.y; ef[2] = v0.z; ef[3] = v0.w;
            ef[4] = v1.x; ef[5] = v1.y; ef[6] = v1.z; ef[7] = v1.w;
        }

        // ---- h[e, 2t+hpar] for t = 0..15 (the 16 hidden units this lane feeds) ----
        float hv[16];
#pragma unroll
        for (int t = 0; t < 16; ++t) {
            const int hd = 2 * t + hpar;
            float a = sb1[hd];
#pragma unroll
            for (int k = 0; k < 8; ++k)
                a = fmaf(ef[k], sW1[k * 32 + hd], a);
            hv[t] = fmaxf(a, 0.f);
        }

        // ---- K loop: z-frag = bf16(h * x-slice), MFMA accumulate ----
        f32x4_t acc = {0.f, 0.f, 0.f, 0.f};
#pragma unroll
        for (int s = 0; s < 16; ++s) {
            bf16x8_t a;
            const float h = hv[s];
#pragma unroll
            for (int t = 0; t < 8; ++t)
                a[t] = (short)f2bf(h * xf[t]);
            acc = __builtin_amdgcn_mfma_f32_16x16x32_bf16(a, bfrag[s], acc, 0, 0, 0);
        }
        // b2 fold step: A rows k'<16 must be x (h==1); rows >=16 multiply zero B.
        acc = __builtin_amdgcn_mfma_f32_16x16x32_bf16(xbf, bfrag[16], acc, 0, 0, 0);

        // ---- scatter: lane holds D[row = q*4 + r][col = c] ----
#pragma unroll
        for (int r = 0; r < 4; ++r) {
            const int er  = q * 4 + r;
            const int eid = base + er;
            if (eid < n_edges) {
                const int tgt = idx_i[eid];
                atomicAdd(out + (size_t)tgt * 16 + c, acc[r]);
            }
        }
    }
}

extern "C" void kernel_launch(void* const* d_in, const int* in_sizes, int n_in,
                              void* d_out, int out_size, void* d_ws, size_t ws_size,
                              hipStream_t stream) {
    const float* x     = (const float*)d_in[0];
    const float* e     = (const float*)d_in[1];
    const int*   idx_i = (const int*)d_in[2];
    const int*   idx_j = (const int*)d_in[3];
    const float* W1    = (const float*)d_in[4];
    const float* b1    = (const float*)d_in[5];
    const float* W2    = (const float*)d_in[6];
    const float* b2    = (const float*)d_in[7];
    const float* rootk = (const float*)d_in[8];
    const float* bias  = (const float*)d_in[9];

    int n_nodes = in_sizes[0] / 16;
    int n_edges = in_sizes[2];
    int n_groups = (n_edges + 15) / 16;

    float* out = (float*)d_out;

    int blocksA = (n_nodes + 255) / 256;
    root_init_kernel<<<blocksA, 256, 0, stream>>>(x, rootk, bias, out, n_nodes);

    // 1024 blocks x 4 waves = 4096 waves; each wave handles ~8 groups (B-frags amortized).
    int blocksB = 1024;
    edge_mfma_kernel<<<blocksB, 256, 0, stream>>>(x, e, idx_i, idx_j, W1, b1, W2, b2,
                                                  out, n_edges, n_groups);
}

// Round 4
// 65.015 us; speedup vs baseline: 7.1058x; 1.1915x over previous
//
#include <hip/hip_runtime.h>

typedef __attribute__((ext_vector_type(8))) short bf16x8_t;   // 8 bf16 (4 VGPRs)
typedef __attribute__((ext_vector_type(4))) float f32x4_t;    // MFMA accumulator

__device__ __forceinline__ unsigned short f2bf(float f) {
    union { float f; unsigned int i; } v; v.f = f;
    unsigned int u = v.i;
    return (unsigned short)((u + 0x7FFFu + ((u >> 16) & 1u)) >> 16);   // RNE
}

// packed f32x2 -> bf16x2 (D.lo = bf16(lo), D.hi = bf16(hi))
__device__ __forceinline__ unsigned int cvt_pk_bf16(float lo, float hi) {
    unsigned int r;
    asm("v_cvt_pk_bf16_f32 %0, %1, %2" : "=v"(r) : "v"(lo), "v"(hi));
    return r;
}

// ============ kernel 1: fused {h-precompute | root-init | W2 fragment prep} ============
// Block ranges: [0, h_blocks) -> hP, [h_blocks, h_blocks+root_blocks) -> root, last -> W2p.
__global__ __launch_bounds__(256) void prep_kernel(
    const float* __restrict__ x,       // [N,16]
    const float* __restrict__ efeat,   // [E,8]
    const float* __restrict__ W1,      // [8,32]
    const float* __restrict__ b1,      // [32]
    const float* __restrict__ W2,      // [32,256]
    const float* __restrict__ b2,      // [256]
    const float* __restrict__ rootk,   // [16,16]
    const float* __restrict__ bias,    // [16]
    float* __restrict__ out,           // [N,16]
    unsigned short* __restrict__ W2p,  // [17][4][16][8] bf16
    float* __restrict__ hP,            // [E][2][16] f32 (parity-split h), optional
    int n_nodes, int n_edges, int h_blocks, int root_blocks)
{
    const int tid = threadIdx.x;
    const int bid = blockIdx.x;

    if (bid < h_blocks) {
        // ---- h part: hP[e][par][t] = relu(b1[2t+par] + sum_k e[k]*W1[k][2t+par]) ----
        __shared__ float sW1t[256];   // [hd][k] transposed
        __shared__ float sb1[32];
        if (tid < 256) sW1t[tid] = W1[(tid & 7) * 32 + (tid >> 3)];
        if (tid < 32)  sb1[tid] = b1[tid];
        __syncthreads();

        int e = bid * 256 + tid;
        if (e >= n_edges) return;

        const float* ep = efeat + (size_t)e * 8;
        float4 v0 = *reinterpret_cast<const float4*>(ep);
        float4 v1 = *reinterpret_cast<const float4*>(ep + 4);
        float ef[8] = {v0.x, v0.y, v0.z, v0.w, v1.x, v1.y, v1.z, v1.w};

        float ph[32];
#pragma unroll
        for (int hd = 0; hd < 32; ++hd) {
            float a = sb1[hd];
#pragma unroll
            for (int k = 0; k < 8; ++k)
                a = fmaf(ef[k], sW1t[hd * 8 + k], a);
            ph[hd] = fmaxf(a, 0.f);
        }

        float* hp = hP + (size_t)e * 32;
        *reinterpret_cast<float4*>(hp + 0)  = make_float4(ph[0],  ph[2],  ph[4],  ph[6]);
        *reinterpret_cast<float4*>(hp + 4)  = make_float4(ph[8],  ph[10], ph[12], ph[14]);
        *reinterpret_cast<float4*>(hp + 8)  = make_float4(ph[16], ph[18], ph[20], ph[22]);
        *reinterpret_cast<float4*>(hp + 12) = make_float4(ph[24], ph[26], ph[28], ph[30]);
        *reinterpret_cast<float4*>(hp + 16) = make_float4(ph[1],  ph[3],  ph[5],  ph[7]);
        *reinterpret_cast<float4*>(hp + 20) = make_float4(ph[9],  ph[11], ph[13], ph[15]);
        *reinterpret_cast<float4*>(hp + 24) = make_float4(ph[17], ph[19], ph[21], ph[23]);
        *reinterpret_cast<float4*>(hp + 28) = make_float4(ph[25], ph[27], ph[29], ph[31]);
    } else if (bid < h_blocks + root_blocks) {
        // ---- root part: out[n,:] = x[n]@root_kernel + bias ----
        __shared__ float sR[256];
        __shared__ float sB[16];
        if (tid < 256) sR[tid] = rootk[tid];
        if (tid < 16)  sB[tid] = bias[tid];
        __syncthreads();

        int nid = (bid - h_blocks) * 256 + tid;
        if (nid >= n_nodes) return;

        const float* xp = x + (size_t)nid * 16;
        float xf[16];
#pragma unroll
        for (int f = 0; f < 16; f += 4) {
            float4 v = *reinterpret_cast<const float4*>(xp + f);
            xf[f] = v.x; xf[f + 1] = v.y; xf[f + 2] = v.z; xf[f + 3] = v.w;
        }
        float o[16];
#pragma unroll
        for (int c = 0; c < 16; ++c) o[c] = sB[c];
#pragma unroll
        for (int f = 0; f < 16; ++f) {
            float p = xf[f];
#pragma unroll
            for (int c = 0; c < 16; ++c)
                o[c] = fmaf(p, sR[f * 16 + c], o[c]);
        }
        float* dst = out + (size_t)nid * 16;
#pragma unroll
        for (int c = 0; c < 16; c += 4)
            *reinterpret_cast<float4*>(dst + c) = make_float4(o[c], o[c+1], o[c+2], o[c+3]);
    } else {
        // ---- W2p part: per-lane B fragments, W2p[((s*4+q)*16+c)*8 + j] ----
        for (int it = tid; it < 17 * 64; it += 256) {
            int s = it >> 6, q = (it >> 4) & 3, cc = it & 15;
            int hpar = q >> 1, f0 = (q & 1) * 8;
            union { unsigned short h[8]; uint4 u; } pk;
#pragma unroll
            for (int jj = 0; jj < 8; ++jj) {
                float val;
                if (s < 16)       val = W2[(2 * s + hpar) * 256 + (f0 + jj) * 16 + cc];
                else if (hpar==0) val = b2[(f0 + jj) * 16 + cc];
                else              val = 0.f;
                pk.h[jj] = f2bf(val);
            }
            *reinterpret_cast<uint4*>(W2p + it * 8) = pk.u;
        }
    }
}

// ============ kernel 2: MFMA edge kernel (one wave = 16 edges/group, grid-stride) ============
// msg = z @ W2r, z[e, hd*16+f] = h[e,hd]*x[e,f]; K = 512 + 16 (b2 fold).
template<int PRE_H>
__global__ __launch_bounds__(256) void edge_mfma_kernel(
    const float* __restrict__ x,       // [N,16]
    const float* __restrict__ efeat,   // [E,8]   (fallback only)
    const int*   __restrict__ idx_i,
    const int*   __restrict__ idx_j,
    const float* __restrict__ W1,      // (fallback only)
    const float* __restrict__ b1,      // (fallback only)
    const unsigned short* __restrict__ W2p,
    const float* __restrict__ hP,      // [E][2][16] (PRE_H only)
    float* __restrict__ out,           // [N,16], pre-initialized with root term
    int n_edges, int n_groups)
{
    __shared__ float sW1t[256];
    __shared__ float sb1[32];
    if (!PRE_H) {
        if (threadIdx.x < 256) sW1t[threadIdx.x] = W1[(threadIdx.x & 7) * 32 + (threadIdx.x >> 3)];
        if (threadIdx.x < 32)  sb1[threadIdx.x] = b1[threadIdx.x];
        __syncthreads();
    }

    const int lane = threadIdx.x & 63;
    const int q    = lane >> 4;       // K-group of the fragment
    const int c    = lane & 15;       // A row (edge slot) / B,D col
    const int hpar = q >> 1;          // hidden-unit parity this lane feeds
    const int f0   = (q & 1) * 8;     // input-feature half

    // B fragments: 17 coalesced 16B loads (prepped layout, bf16)
    bf16x8_t bfrag[17];
    {
        const bf16x8_t* wp = reinterpret_cast<const bf16x8_t*>(W2p) + (q * 16 + c);
#pragma unroll
        for (int s = 0; s < 17; ++s) bfrag[s] = wp[s * 64];
    }

    const int gwave  = blockIdx.x * 4 + (threadIdx.x >> 6);
    const int nwaves = gridDim.x * 4;

    for (int g = gwave; g < n_groups; g += nwaves) {
        const int base = g * 16;
        const int eid  = base + c;
        const bool va  = (eid < n_edges);
        const int  el  = va ? eid : (n_edges - 1);
        const int  j   = idx_j[el];

        // x[j, f0..f0+7]
        float xf[8];
        {
            const float* xp = x + (size_t)j * 16 + f0;
            float4 a0 = *reinterpret_cast<const float4*>(xp);
            float4 a1 = *reinterpret_cast<const float4*>(xp + 4);
            xf[0]=a0.x; xf[1]=a0.y; xf[2]=a0.z; xf[3]=a0.w;
            xf[4]=a1.x; xf[5]=a1.y; xf[6]=a1.z; xf[7]=a1.w;
            if (!va) {
#pragma unroll
                for (int t = 0; t < 8; ++t) xf[t] = 0.f;  // invalid edge -> z rows = 0
            }
        }

        // h[edge c][2t+hpar], t = 0..15
        float hv[16];
        if (PRE_H) {
            const float* hp = hP + (size_t)el * 32 + hpar * 16;
            float4 h0 = *reinterpret_cast<const float4*>(hp);
            float4 h1 = *reinterpret_cast<const float4*>(hp + 4);
            float4 h2 = *reinterpret_cast<const float4*>(hp + 8);
            float4 h3 = *reinterpret_cast<const float4*>(hp + 12);
            hv[0]=h0.x; hv[1]=h0.y; hv[2]=h0.z; hv[3]=h0.w;
            hv[4]=h1.x; hv[5]=h1.y; hv[6]=h1.z; hv[7]=h1.w;
            hv[8]=h2.x; hv[9]=h2.y; hv[10]=h2.z; hv[11]=h2.w;
            hv[12]=h3.x; hv[13]=h3.y; hv[14]=h3.z; hv[15]=h3.w;
        } else {
            const float* ep = efeat + (size_t)el * 8;
            float4 v0 = *reinterpret_cast<const float4*>(ep);
            float4 v1 = *reinterpret_cast<const float4*>(ep + 4);
            float ef[8] = {v0.x, v0.y, v0.z, v0.w, v1.x, v1.y, v1.z, v1.w};
#pragma unroll
            for (int t = 0; t < 16; ++t) {
                const int hd = 2 * t + hpar;
                float a = sb1[hd];
#pragma unroll
                for (int k = 0; k < 8; ++k)
                    a = fmaf(ef[k], sW1t[hd * 8 + k], a);
                hv[t] = fmaxf(a, 0.f);
            }
        }

        // scatter targets for rows q*4..q*4+3
        int t0, t1, t2, t3;
        if (base + 16 <= n_edges) {
            int4 tv = *reinterpret_cast<const int4*>(idx_i + base + q * 4);
            t0 = tv.x; t1 = tv.y; t2 = tv.z; t3 = tv.w;
        } else {
            const int eb = base + q * 4;
            t0 = (eb + 0 < n_edges) ? idx_i[eb + 0] : 0;
            t1 = (eb + 1 < n_edges) ? idx_i[eb + 1] : 0;
            t2 = (eb + 2 < n_edges) ? idx_i[eb + 2] : 0;
            t3 = (eb + 3 < n_edges) ? idx_i[eb + 3] : 0;
        }

        // K loop, two independent accumulator chains
        f32x4_t acc0 = {0.f, 0.f, 0.f, 0.f};
        f32x4_t acc1 = {0.f, 0.f, 0.f, 0.f};
        union { bf16x8_t bf; unsigned int u[4]; } afr;
#pragma unroll
        for (int s = 0; s < 16; s += 2) {
            float h = hv[s];
            afr.u[0] = cvt_pk_bf16(h * xf[0], h * xf[1]);
            afr.u[1] = cvt_pk_bf16(h * xf[2], h * xf[3]);
            afr.u[2] = cvt_pk_bf16(h * xf[4], h * xf[5]);
            afr.u[3] = cvt_pk_bf16(h * xf[6], h * xf[7]);
            acc0 = __builtin_amdgcn_mfma_f32_16x16x32_bf16(afr.bf, bfrag[s], acc0, 0, 0, 0);
            h = hv[s + 1];
            afr.u[0] = cvt_pk_bf16(h * xf[0], h * xf[1]);
            afr.u[1] = cvt_pk_bf16(h * xf[2], h * xf[3]);
            afr.u[2] = cvt_pk_bf16(h * xf[4], h * xf[5]);
            afr.u[3] = cvt_pk_bf16(h * xf[6], h * xf[7]);
            acc1 = __builtin_amdgcn_mfma_f32_16x16x32_bf16(afr.bf, bfrag[s + 1], acc1, 0, 0, 0);
        }
        // b2 fold (A = x, B rows >=16 are zero)
        afr.u[0] = cvt_pk_bf16(xf[0], xf[1]);
        afr.u[1] = cvt_pk_bf16(xf[2], xf[3]);
        afr.u[2] = cvt_pk_bf16(xf[4], xf[5]);
        afr.u[3] = cvt_pk_bf16(xf[6], xf[7]);
        acc0 = __builtin_amdgcn_mfma_f32_16x16x32_bf16(afr.bf, bfrag[16], acc0, 0, 0, 0);

        const int eb = base + q * 4;
        const float r0 = acc0[0] + acc1[0];
        const float r1 = acc0[1] + acc1[1];
        const float r2 = acc0[2] + acc1[2];
        const float r3 = acc0[3] + acc1[3];
        if (eb + 0 < n_edges) atomicAdd(out + (size_t)t0 * 16 + c, r0);
        if (eb + 1 < n_edges) atomicAdd(out + (size_t)t1 * 16 + c, r1);
        if (eb + 2 < n_edges) atomicAdd(out + (size_t)t2 * 16 + c, r2);
        if (eb + 3 < n_edges) atomicAdd(out + (size_t)t3 * 16 + c, r3);
    }
}

extern "C" void kernel_launch(void* const* d_in, const int* in_sizes, int n_in,
                              void* d_out, int out_size, void* d_ws, size_t ws_size,
                              hipStream_t stream) {
    const float* x     = (const float*)d_in[0];
    const float* e     = (const float*)d_in[1];
    const int*   idx_i = (const int*)d_in[2];
    const int*   idx_j = (const int*)d_in[3];
    const float* W1    = (const float*)d_in[4];
    const float* b1    = (const float*)d_in[5];
    const float* W2    = (const float*)d_in[6];
    const float* b2    = (const float*)d_in[7];
    const float* rootk = (const float*)d_in[8];
    const float* bias  = (const float*)d_in[9];

    int n_nodes  = in_sizes[0] / 16;
    int n_edges  = in_sizes[2];
    int n_groups = (n_edges + 15) / 16;

    float* out = (float*)d_out;

    unsigned short* W2p = (unsigned short*)d_ws;                 // 17408 B used
    float* hP = (float*)((char*)d_ws + 32768);
    size_t need_h = 32768 + (size_t)n_edges * 32 * sizeof(float);
    const int use_preh = (ws_size >= need_h) ? 1 : 0;

    int h_blocks    = use_preh ? (n_edges + 255) / 256 : 0;
    int root_blocks = (n_nodes + 255) / 256;
    int grid1 = h_blocks + root_blocks + 1;
    prep_kernel<<<grid1, 256, 0, stream>>>(x, e, W1, b1, W2, b2, rootk, bias,
                                           out, W2p, hP, n_nodes, n_edges,
                                           h_blocks, root_blocks);

    const int blocksB = 2048;   // 8192 waves, ~3.8 groups each
    if (use_preh)
        edge_mfma_kernel<1><<<blocksB, 256, 0, stream>>>(x, e, idx_i, idx_j, W1, b1,
                                                         W2p, hP, out, n_edges, n_groups);
    else
        edge_mfma_kernel<0><<<blocksB, 256, 0, stream>>>(x, e, idx_i, idx_j, W1, b1,
                                                         W2p, hP, out, n_edges, n_groups);
}

// Round 5
// 46.483 us; speedup vs baseline: 9.9388x; 1.3987x over previous
//
#include <hip/hip_runtime.h>

typedef __attribute__((ext_vector_type(8))) short bf16x8_t;   // 8 bf16 (4 VGPRs)
typedef __attribute__((ext_vector_type(4))) float f32x4_t;    // MFMA accumulator

__device__ __forceinline__ unsigned short f2bf(float f) {
    union { float f; unsigned int i; } v; v.f = f;
    unsigned int u = v.i;
    return (unsigned short)((u + 0x7FFFu + ((u >> 16) & 1u)) >> 16);   // RNE
}

__device__ __forceinline__ unsigned int cvt_pk_bf16(float lo, float hi) {
    unsigned int r;
    asm("v_cvt_pk_bf16_f32 %0, %1, %2" : "=v"(r) : "v"(lo), "v"(hi));
    return r;
}

// d_ws layout (u16 elements):
//   [0      .. 1024)  W1p: h-MFMA A-frags, [half][lane][8] bf16  (2 KB)
//   [1024   .. 9728)  W2p: main-MFMA B-frags, [s=0..16][lane][8] bf16 (17 KB)

// ============ kernel 1: fused {root-init | fragment-table prep} ============
__global__ __launch_bounds__(256) void prep_kernel(
    const float* __restrict__ x,       // [N,16]
    const float* __restrict__ W1,      // [8,32]
    const float* __restrict__ b1,      // [32]
    const float* __restrict__ W2,      // [32,256]
    const float* __restrict__ b2,      // [256]
    const float* __restrict__ rootk,   // [16,16]
    const float* __restrict__ bias,    // [16]
    float* __restrict__ out,           // [N,16]
    unsigned short* __restrict__ tab,  // d_ws
    int n_nodes, int root_blocks)
{
    const int tid = threadIdx.x;
    const int bid = blockIdx.x;

    if (bid < root_blocks) {
        // ---- root part: out[n,:] = x[n]@root_kernel + bias ----
        __shared__ float sR[256];
        __shared__ float sB[16];
        if (tid < 256) sR[tid] = rootk[tid];
        if (tid < 16)  sB[tid] = bias[tid];
        __syncthreads();

        int nid = bid * 256 + tid;
        if (nid >= n_nodes) return;

        const float* xp = x + (size_t)nid * 16;
        float xf[16];
#pragma unroll
        for (int f = 0; f < 16; f += 4) {
            float4 v = *reinterpret_cast<const float4*>(xp + f);
            xf[f] = v.x; xf[f + 1] = v.y; xf[f + 2] = v.z; xf[f + 3] = v.w;
        }
        float o[16];
#pragma unroll
        for (int cc = 0; cc < 16; ++cc) o[cc] = sB[cc];
#pragma unroll
        for (int f = 0; f < 16; ++f) {
            float p = xf[f];
#pragma unroll
            for (int cc = 0; cc < 16; ++cc)
                o[cc] = fmaf(p, sR[f * 16 + cc], o[cc]);
        }
        float* dst = out + (size_t)nid * 16;
#pragma unroll
        for (int cc = 0; cc < 16; cc += 4)
            *reinterpret_cast<float4*>(dst + cc) = make_float4(o[cc], o[cc+1], o[cc+2], o[cc+3]);
    } else {
        // ---- fragment tables: 19 groups of 64 lanes ----
        for (int it = tid; it < 64 * 19; it += 256) {
            int grp  = it >> 6;         // 0,1 -> W1p halves; 2..18 -> W2p steps
            int lane = it & 63;
            int q = lane >> 4, cc = lane & 15;
            union { unsigned short h[8]; uint4 u; } pk;
            if (grp < 2) {
                int hh = grp;           // half
#pragma unroll
                for (int j = 0; j < 8; ++j) {
                    float v = 0.f;
                    if (q == 0)              v = W1[j * 32 + cc + 16 * hh];
                    else if (q == 1 && j==0) v = b1[cc + 16 * hh];
                    pk.h[j] = f2bf(v);
                }
                *reinterpret_cast<uint4*>(tab + ((size_t)hh * 64 + lane) * 8) = pk.u;
            } else {
                int s = grp - 2;        // K-step
#pragma unroll
                for (int j = 0; j < 8; ++j) {
                    float v;
                    if (s < 16) {
                        int hd = (j < 4) ? (4 * q + j) : (4 * q + 12 + j);  // perm
                        v = W2[hd * 256 + s * 16 + cc];
                    } else {
                        v = (q < 2) ? b2[(q * 8 + j) * 16 + cc] : 0.f;       // b2 fold
                    }
                    pk.h[j] = f2bf(v);
                }
                *reinterpret_cast<uint4*>(tab + 1024 + ((size_t)s * 64 + lane) * 8) = pk.u;
            }
        }
    }
}

// ============ kernel 2: MFMA edge kernel, in-register h, software-pipelined ============
__global__ __launch_bounds__(256) void edge_mfma_kernel(
    const float* __restrict__ x,       // [N,16]
    const float* __restrict__ efeat,   // [E,8]
    const int*   __restrict__ idx_i,
    const int*   __restrict__ idx_j,
    const unsigned short* __restrict__ tab,
    float* __restrict__ out,           // [N,16], pre-initialized with root term
    int n_edges, int n_groups)
{
    const int lane = threadIdx.x & 63;
    const int q = lane >> 4;
    const int c = lane & 15;

    // ---- per-wave fragment preload ----
    const bf16x8_t* w1f = reinterpret_cast<const bf16x8_t*>(tab) + lane;
    const bf16x8_t aW1_0 = w1f[0];
    const bf16x8_t aW1_1 = w1f[64];
    const bf16x8_t* w2f = reinterpret_cast<const bf16x8_t*>(tab + 1024) + lane;
    bf16x8_t bW2[17];
#pragma unroll
    for (int s = 0; s < 17; ++s) bW2[s] = w2f[s * 64];

    const unsigned int c1 = (q == 1) ? 0x00003F80u : 0u;   // bf16(1.0) one-hot for b1 row
    const bool isq0 = (q == 0);
    const bool qodd = (q & 1);

    int g = blockIdx.x * 4 + (threadIdx.x >> 6);
    const int nw = gridDim.x * 4;
    if (g >= n_groups) return;

    // prologue: first group's source index
    int  eid = g * 16 + c;
    bool va  = (eid < n_edges);
    int  el  = va ? eid : (n_edges - 1);
    int  jsrc = idx_j[el];

    for (; g < n_groups; g += nw) {
        const int base = g * 16;

        // ---- issue current group's loads ----
        const float* xp = x + (size_t)jsrc * 16;
        float4 x0 = *reinterpret_cast<const float4*>(xp);
        float4 x1 = *reinterpret_cast<const float4*>(xp + 4);
        float4 x2 = *reinterpret_cast<const float4*>(xp + 8);
        float4 x3 = *reinterpret_cast<const float4*>(xp + 12);
        const float* ep = efeat + (size_t)el * 8;
        float4 e0 = *reinterpret_cast<const float4*>(ep);
        float4 e1 = *reinterpret_cast<const float4*>(ep + 4);
        int t0, t1, t2, t3;
        if (base + 16 <= n_edges) {
            int4 tv = *reinterpret_cast<const int4*>(idx_i + base + q * 4);
            t0 = tv.x; t1 = tv.y; t2 = tv.z; t3 = tv.w;
        } else {
            const int eb = base + q * 4;
            t0 = (eb + 0 < n_edges) ? idx_i[eb + 0] : 0;
            t1 = (eb + 1 < n_edges) ? idx_i[eb + 1] : 0;
            t2 = (eb + 2 < n_edges) ? idx_i[eb + 2] : 0;
            t3 = (eb + 3 < n_edges) ? idx_i[eb + 3] : 0;
        }

        // ---- prefetch next group's source index (hides gather dependency) ----
        const int gn = g + nw;
        int  eidn = gn * 16 + c;
        bool van  = (eidn < n_edges);
        int  eln  = van ? eidn : (n_edges - 1);
        int  jn   = (gn < n_groups) ? idx_j[eln] : 0;

        // ---- h via MFMA: D[hd_r][edge] = relu-pre; lane owns hd {4q..4q+3, +16} ----
        union { bf16x8_t bf; unsigned int u[4]; } bB;
        {
            unsigned int ef0 = cvt_pk_bf16(e0.x, e0.y);
            unsigned int ef1 = cvt_pk_bf16(e0.z, e0.w);
            unsigned int ef2 = cvt_pk_bf16(e1.x, e1.y);
            unsigned int ef3 = cvt_pk_bf16(e1.z, e1.w);
            bB.u[0] = isq0 ? ef0 : c1;
            bB.u[1] = isq0 ? ef1 : 0u;
            bB.u[2] = isq0 ? ef2 : 0u;
            bB.u[3] = isq0 ? ef3 : 0u;
        }
        f32x4_t z4 = {0.f, 0.f, 0.f, 0.f};
        f32x4_t h0 = __builtin_amdgcn_mfma_f32_16x16x32_bf16(aW1_0, bB.bf, z4, 0, 0, 0);
        f32x4_t h1 = __builtin_amdgcn_mfma_f32_16x16x32_bf16(aW1_1, bB.bf, z4, 0, 0, 0);

        float hown[8];
#pragma unroll
        for (int r = 0; r < 4; ++r) {
            hown[r]     = fmaxf(h0[r], 0.f);
            hown[4 + r] = fmaxf(h1[r], 0.f);
        }

        // ---- x fragment (zero rows for invalid edges) ----
        float xf[16];
        xf[0]=x0.x; xf[1]=x0.y; xf[2]=x0.z; xf[3]=x0.w;
        xf[4]=x1.x; xf[5]=x1.y; xf[6]=x1.z; xf[7]=x1.w;
        xf[8]=x2.x; xf[9]=x2.y; xf[10]=x2.z; xf[11]=x2.w;
        xf[12]=x3.x; xf[13]=x3.y; xf[14]=x3.z; xf[15]=x3.w;
        if (!va) {
#pragma unroll
            for (int t = 0; t < 16; ++t) xf[t] = 0.f;
        }

        // ---- b2-fold A fragment: bf16(x[f]), f = q-half selected ----
        union { bf16x8_t bf; unsigned int u[4]; } xb;
        {
            float xs0 = qodd ? xf[8]  : xf[0];
            float xs1 = qodd ? xf[9]  : xf[1];
            float xs2 = qodd ? xf[10] : xf[2];
            float xs3 = qodd ? xf[11] : xf[3];
            float xs4 = qodd ? xf[12] : xf[4];
            float xs5 = qodd ? xf[13] : xf[5];
            float xs6 = qodd ? xf[14] : xf[6];
            float xs7 = qodd ? xf[15] : xf[7];
            xb.u[0] = cvt_pk_bf16(xs0, xs1);
            xb.u[1] = cvt_pk_bf16(xs2, xs3);
            xb.u[2] = cvt_pk_bf16(xs4, xs5);
            xb.u[3] = cvt_pk_bf16(xs6, xs7);
        }

        // ---- K loop: A[c][q*8+j] = bf16(hown[j] * x[f=s]), two acc chains ----
        f32x4_t acc0 = {0.f, 0.f, 0.f, 0.f};
        f32x4_t acc1 = {0.f, 0.f, 0.f, 0.f};
        union { bf16x8_t bf; unsigned int u[4]; } afr;
#pragma unroll
        for (int s = 0; s < 16; s += 2) {
            float xs = xf[s];
            afr.u[0] = cvt_pk_bf16(hown[0] * xs, hown[1] * xs);
            afr.u[1] = cvt_pk_bf16(hown[2] * xs, hown[3] * xs);
            afr.u[2] = cvt_pk_bf16(hown[4] * xs, hown[5] * xs);
            afr.u[3] = cvt_pk_bf16(hown[6] * xs, hown[7] * xs);
            acc0 = __builtin_amdgcn_mfma_f32_16x16x32_bf16(afr.bf, bW2[s], acc0, 0, 0, 0);
            xs = xf[s + 1];
            afr.u[0] = cvt_pk_bf16(hown[0] * xs, hown[1] * xs);
            afr.u[1] = cvt_pk_bf16(hown[2] * xs, hown[3] * xs);
            afr.u[2] = cvt_pk_bf16(hown[4] * xs, hown[5] * xs);
            afr.u[3] = cvt_pk_bf16(hown[6] * xs, hown[7] * xs);
            acc1 = __builtin_amdgcn_mfma_f32_16x16x32_bf16(afr.bf, bW2[s + 1], acc1, 0, 0, 0);
        }
        acc0 = __builtin_amdgcn_mfma_f32_16x16x32_bf16(xb.bf, bW2[16], acc0, 0, 0, 0);

        // ---- scatter: lane holds msg[edge base+q*4+r][channel c] ----
        const int eb = base + q * 4;
        const float r0 = acc0[0] + acc1[0];
        const float r1 = acc0[1] + acc1[1];
        const float r2 = acc0[2] + acc1[2];
        const float r3 = acc0[3] + acc1[3];
        if (eb + 0 < n_edges) atomicAdd(out + (size_t)t0 * 16 + c, r0);
        if (eb + 1 < n_edges) atomicAdd(out + (size_t)t1 * 16 + c, r1);
        if (eb + 2 < n_edges) atomicAdd(out + (size_t)t2 * 16 + c, r2);
        if (eb + 3 < n_edges) atomicAdd(out + (size_t)t3 * 16 + c, r3);

        jsrc = jn; el = eln; va = van;
    }
}

extern "C" void kernel_launch(void* const* d_in, const int* in_sizes, int n_in,
                              void* d_out, int out_size, void* d_ws, size_t ws_size,
                              hipStream_t stream) {
    const float* x     = (const float*)d_in[0];
    const float* e     = (const float*)d_in[1];
    const int*   idx_i = (const int*)d_in[2];
    const int*   idx_j = (const int*)d_in[3];
    const float* W1    = (const float*)d_in[4];
    const float* b1    = (const float*)d_in[5];
    const float* W2    = (const float*)d_in[6];
    const float* b2    = (const float*)d_in[7];
    const float* rootk = (const float*)d_in[8];
    const float* bias  = (const float*)d_in[9];

    int n_nodes  = in_sizes[0] / 16;
    int n_edges  = in_sizes[2];
    int n_groups = (n_edges + 15) / 16;

    float* out = (float*)d_out;
    unsigned short* tab = (unsigned short*)d_ws;   // 19.5 KB used

    int root_blocks = (n_nodes + 255) / 256;
    prep_kernel<<<root_blocks + 1, 256, 0, stream>>>(x, W1, b1, W2, b2, rootk, bias,
                                                     out, tab, n_nodes, root_blocks);

    // 1024 blocks x 4 waves = 4096 waves; ~7.6 groups each (pipeline stays warm)
    edge_mfma_kernel<<<1024, 256, 0, stream>>>(x, e, idx_i, idx_j, tab, out,
                                               n_edges, n_groups);
}